// Round 6
// baseline (333.499 us; speedup 1.0000x reference)
//
#include <hip/hip_runtime.h>

#define B_   2
#define CIN  16
#define HIN  384
#define WIN  1280
#define CO   24
#define HQ   96
#define WL   320
#define WR   1280
#define DMAX 64

__device__ __forceinline__ float lk(float v) { return v >= 0.f ? v : 0.2f * v; }

// ============ Fused em kernel: blocks 0..959 = right branch, 960..1439 = left =
// Both paths: leaky(conv4x4) -> rc 1x1 -> leaky, LDS union (weights -> em acts)
__global__ __launch_bounds__(256) void k_em(
    const float* __restrict__ xl, const float* __restrict__ xr_in,
    const float* __restrict__ w_em, const float* __restrict__ b_em,
    const float* __restrict__ w_rc, const float* __restrict__ b_rc,
    float* __restrict__ outl, float* __restrict__ outr)
{
    __shared__ float smem[CO * CIN * 16];  // em weights during conv, then em acts
    __shared__ float swt[CO * CO];         // rc weights transposed [c][o]
    __shared__ float sbe[CO], sbr[CO];

    for (int i = threadIdx.x; i < CO * CIN * 16; i += 256) smem[i] = w_em[i];
    for (int i = threadIdx.x; i < CO * CO; i += 256) swt[i] = w_rc[(i % CO) * CO + (i / CO)];
    if (threadIdx.x < CO) { sbe[threadIdx.x] = b_em[threadIdx.x]; sbr[threadIdx.x] = b_rc[threadIdx.x]; }
    __syncthreads();

    const int t = threadIdx.x;

    if (blockIdx.x < 960) {
        // ---------------- right branch: 4x4 s(4,1), width pad (1,2) ----------
        // 64 lanes (4 adjacent px each) x 4 wave-quarters (6 out-ch each);
        // block covers 256 consecutive px of one row
        const int L = t & 63, quarter = t >> 6;
        const int obase = quarter * 6;
        const int row = blockIdx.x / 5, jbase = (blockIdx.x % 5) * 256;
        const int b = row / HQ, h = row % HQ;

        const bool vm1 = jbase > 0;              // col jbase-1 valid
        const bool vp4 = (jbase + 256) < WIN;    // col jbase+256 valid
        const bool vp5 = (jbase + 257) < WIN;    // col jbase+257 valid

        float acc[4][6];
#pragma unroll
        for (int k = 0; k < 4; ++k)
#pragma unroll
            for (int oo = 0; oo < 6; ++oo) acc[k][oo] = sbe[obase + oo];

        for (int c = 0; c < CIN; ++c) {
#pragma unroll
            for (int kh = 0; kh < 4; ++kh) {
                const float* xr = xr_in + ((size_t)(b * CIN + c) * HIN + 4 * h + kh) * WIN + jbase;
                const float4 v = *(const float4*)(xr + 4 * L);
                // neighbors via wave shuffles (cols 4L-1, 4L+4, 4L+5)
                float in0 = __shfl_up(v.w, 1);
                float in5 = __shfl_down(v.x, 1);
                float in6 = __shfl_down(v.y, 1);
                if (L == 0)  in0 = vm1 ? xr[-1] : 0.f;
                if (L == 63) { in5 = vp4 ? xr[256] : 0.f; in6 = vp5 ? xr[257] : 0.f; }
                float in[7];
                in[0] = in0; in[1] = v.x; in[2] = v.y; in[3] = v.z; in[4] = v.w;
                in[5] = in5; in[6] = in6;
#pragma unroll
                for (int oo = 0; oo < 6; ++oo) {
                    const float4 wv = *(const float4*)&smem[(((obase + oo) * CIN + c) * 4 + kh) * 4];
#pragma unroll
                    for (int k = 0; k < 4; ++k)
                        acc[k][oo] += in[k] * wv.x + in[k + 1] * wv.y + in[k + 2] * wv.z + in[k + 3] * wv.w;
                }
            }
        }
        __syncthreads();                       // weight reads done before overlay
#pragma unroll
        for (int oo = 0; oo < 6; ++oo) {
            float4 st = make_float4(lk(acc[0][oo]), lk(acc[1][oo]), lk(acc[2][oo]), lk(acc[3][oo]));
            *(float4*)&smem[(obase + oo) * 256 + 4 * L] = st;
        }
        __syncthreads();

        // rc phase: thread <-> px 1:1 (256 px)
        float acc2[CO];
#pragma unroll
        for (int o = 0; o < CO; ++o) acc2[o] = sbr[o];
        for (int c = 0; c < CO; ++c) {
            const float in_c = smem[c * 256 + t];
#pragma unroll
            for (int o = 0; o < CO; ++o) acc2[o] += in_c * swt[c * CO + o];
        }
#pragma unroll
        for (int o = 0; o < CO; ++o)
            outr[((size_t)(b * CO + o) * HQ + h) * WR + jbase + t] = lk(acc2[o]);
    } else {
        // ---------------- left branch: 4x4 s(4,4) VALID ----------------------
        // 128 px * 2 o-halves (12 out-ch each)
        const int half = t >> 7, pxl = t & 127;
        const int obase = half * 12;
        const int flat = (blockIdx.x - 960) * 128 + pxl;   // < 61440
        const int j = flat % WL, h = (flat / WL) % HQ, b = flat / (WL * HQ);

        float acc[12];
#pragma unroll
        for (int oo = 0; oo < 12; ++oo) acc[oo] = sbe[obase + oo];

        for (int c = 0; c < CIN; ++c) {
#pragma unroll
            for (int kh = 0; kh < 4; ++kh) {
                const float4 v = *(const float4*)(xl + ((size_t)(b * CIN + c) * HIN + 4 * h + kh) * WIN + 4 * j);
#pragma unroll
                for (int oo = 0; oo < 12; ++oo) {
                    const float4 wv = *(const float4*)&smem[(((obase + oo) * CIN + c) * 4 + kh) * 4];
                    acc[oo] += v.x * wv.x + v.y * wv.y + v.z * wv.z + v.w * wv.w;
                }
            }
        }
        __syncthreads();
#pragma unroll
        for (int oo = 0; oo < 12; ++oo) smem[(obase + oo) * 128 + pxl] = lk(acc[oo]);
        __syncthreads();

        float acc2[12];
#pragma unroll
        for (int oo = 0; oo < 12; ++oo) acc2[oo] = sbr[obase + oo];
        for (int c = 0; c < CO; ++c) {
            const float in_c = smem[c * 128 + pxl];
#pragma unroll
            for (int oo = 0; oo < 12; ++oo) acc2[oo] += in_c * swt[c * CO + obase + oo];
        }
#pragma unroll
        for (int oo = 0; oo < 12; ++oo)
            outl[((size_t)(b * CO + obase + oo) * HQ + h) * WL + j] = lk(acc2[oo]);
    }
}

// ====== Kernel C: cost volume + min/argmin + tf 1x1 + output assembly ========
// block 256 = 64 j-cols * 4 d-quarters (16 disparities each); grid 960
// fr window staged in LDS phase-permuted: cp = x - (4*j0 - 64);
// addr = ((cp&3)*12+c)*81 + (cp>>2). x<0 -> replicated fr[c][0] (left clip).
// Channel-ascending accumulation == reference (bitwise-identical costs ->
// identical argmin ties); cross-quarter combine ascending dq, strict <.
__global__ __launch_bounds__(256) void k_cost(
    const float* __restrict__ fl, const float* __restrict__ fr,
    const float* __restrict__ wtf, const float* __restrict__ btf,
    float* __restrict__ out, float* __restrict__ cost)
{
    __shared__ float frs[4 * 12 * 81];    // 15552 B
    __shared__ float sbest[256];
    __shared__ int   sbd[256];

    const int t  = threadIdx.x;
    const int j  = t & 63;                 // local col
    const int dq = t >> 6;                 // d-quarter: d in [16*dq, 16*dq+16)
    const int jc = blockIdx.x % 5;
    const int r  = blockIdx.x / 5;
    const int h  = r % HQ, b = r / HQ;
    const int j0 = jc * 64;
    const int jg = j0 + j;                 // global col
    const int colbase = 4 * j0 - 64;       // global col of cp=0

    float acc[16];
#pragma unroll
    for (int dl = 0; dl < 16; ++dl) acc[dl] = 0.f;

    for (int ch = 0; ch < 2; ++ch) {
        const int c0 = ch * 12;
        __syncthreads();
        for (int idx = t; idx < 12 * 320; idx += 256) {
            const int c = idx / 320, cp = idx % 320;
            const int col = colbase + cp;
            const float v = fr[((size_t)(b * CO + c0 + c) * HQ + h) * WR + (col > 0 ? col : 0)];
            frs[((cp & 3) * 12 + c) * 81 + (cp >> 2)] = v;
        }
        __syncthreads();

        for (int c = 0; c < 12; ++c) {
            const float flc = fl[((size_t)(b * CO + c0 + c) * HQ + h) * WL + jg];
#pragma unroll
            for (int p = 0; p < 4; ++p) {
                const int dp0 = (1 - p) & 3;                 // d residue of this phase
                const int q0 = j - 4 * dq + ((65 - dp0) >> 2);
                const int abase = (p * 12 + c) * 81 + q0;
#pragma unroll
                for (int i = 0; i < 4; ++i)
                    acc[dp0 + 4 * i] += fabsf(flc - frs[abase - i]);
            }
        }
    }

    // cost volume writes: d = 16*dq + dl, coalesced across lanes (jg)
    const size_t cb0 = ((size_t)(b * DMAX + 16 * dq) * HQ + h) * WL + jg;
#pragma unroll
    for (int dl = 0; dl < 16; ++dl)
        cost[cb0 + (size_t)dl * (HQ * WL)] = acc[dl];

    // per-thread min / first-occurrence argmin (ascending d within quarter)
    float best = acc[0]; int bdl = 0;
#pragma unroll
    for (int dl = 1; dl < 16; ++dl)
        if (acc[dl] < best) { best = acc[dl]; bdl = dl; }
    sbest[t] = best; sbd[t] = 16 * dq + bdl;
    __syncthreads();

    if (t < 64) {
        float cur = sbest[j]; int curd = sbd[j];
#pragma unroll
        for (int g = 1; g < 4; ++g) {
            const float v = sbest[g * 64 + j];
            if (v < cur) { cur = v; curd = sbd[g * 64 + j]; }
        }
        float flr[CO];
#pragma unroll
        for (int c = 0; c < CO; ++c) flr[c] = fl[((size_t)(b * CO + c) * HQ + h) * WL + jg];
#pragma unroll
        for (int o = 0; o < 13; ++o) {
            float a = btf[o] + wtf[o * 25] * cur;
#pragma unroll
            for (int c = 0; c < CO; ++c) a += wtf[o * 25 + 1 + c] * flr[c];
            out[((size_t)(b * 16 + 3 + o) * HQ + h) * WL + jg] = lk(a);
        }
        out[((size_t)(b * 16 + 0) * HQ + h) * WL + jg] = (float)curd;
        out[((size_t)(b * 16 + 1) * HQ + h) * WL + jg] = 0.f;
        out[((size_t)(b * 16 + 2) * HQ + h) * WL + jg] = 0.f;
    }
}

extern "C" void kernel_launch(void* const* d_in, const int* in_sizes, int n_in,
                              void* d_out, int out_size, void* d_ws, size_t ws_size,
                              hipStream_t stream) {
    const float* fl_in = (const float*)d_in[0];
    const float* fr_in = (const float*)d_in[1];
    // d_in[2] = max_disp (int) -- fixed 64
    const float* w_em = (const float*)d_in[3];
    const float* b_em = (const float*)d_in[4];
    const float* w_rc = (const float*)d_in[5];
    const float* b_rc = (const float*)d_in[6];
    const float* w_tf = (const float*)d_in[7];
    const float* b_tf = (const float*)d_in[8];

    float* out  = (float*)d_out;
    float* cost = out + (size_t)B_ * 16 * HQ * WL;

    float* fl_ws = (float*)d_ws;                               // [2,24,96,320]
    float* fr_ws = fl_ws + (size_t)B_ * CO * HQ * WL;          // [2,24,96,1280]

    hipLaunchKernelGGL(k_em,   dim3(1440), dim3(256), 0, stream,
                       fl_in, fr_in, w_em, b_em, w_rc, b_rc, fl_ws, fr_ws);
    hipLaunchKernelGGL(k_cost, dim3(960),  dim3(256), 0, stream,
                       fl_ws, fr_ws, w_tf, b_tf, out, cost);
}

// Round 7
// 249.979 us; speedup vs baseline: 1.3341x; 1.3341x over previous
//
#include <hip/hip_runtime.h>

#define B_   2
#define CIN  16
#define HIN  384
#define WIN  1280
#define CO   24
#define HQ   96
#define WL   320
#define WR   1280
#define DMAX 64

__device__ __forceinline__ float lk(float v) { return v >= 0.f ? v : 0.2f * v; }

// ============ Kernel A: em_left (4x4 s4,4 VALID) + leaky + rc 1x1 + leaky ====
// block 256 = 128 px * 2 o-halves (12 out-ch each); grid 480  [R5 version, ~17us]
__global__ __launch_bounds__(256) void k_left(
    const float* __restrict__ x, const float* __restrict__ w_em,
    const float* __restrict__ b_em, const float* __restrict__ w_rc,
    const float* __restrict__ b_rc, float* __restrict__ out)
{
    __shared__ float smem[CO * CIN * 16];  // em weights during conv, then em acts
    __shared__ float swt[CO * CO];         // rc weights transposed [c][o]
    __shared__ float sbe[CO], sbr[CO];

    for (int i = threadIdx.x; i < CO * CIN * 16; i += 256) smem[i] = w_em[i];
    for (int i = threadIdx.x; i < CO * CO; i += 256) swt[i] = w_rc[(i % CO) * CO + (i / CO)];
    if (threadIdx.x < CO) { sbe[threadIdx.x] = b_em[threadIdx.x]; sbr[threadIdx.x] = b_rc[threadIdx.x]; }
    __syncthreads();

    const int t = threadIdx.x;
    const int half = t >> 7, pxl = t & 127;
    const int obase = half * 12;
    const int flat = blockIdx.x * 128 + pxl;       // < 61440
    const int j = flat % WL, h = (flat / WL) % HQ, b = flat / (WL * HQ);

    float acc[12];
#pragma unroll
    for (int oo = 0; oo < 12; ++oo) acc[oo] = sbe[obase + oo];

    for (int c = 0; c < CIN; ++c) {
#pragma unroll
        for (int kh = 0; kh < 4; ++kh) {
            const float4 v = *(const float4*)(x + ((size_t)(b * CIN + c) * HIN + 4 * h + kh) * WIN + 4 * j);
#pragma unroll
            for (int oo = 0; oo < 12; ++oo) {
                const float4 wv = *(const float4*)&smem[(((obase + oo) * CIN + c) * 4 + kh) * 4];
                acc[oo] += v.x * wv.x + v.y * wv.y + v.z * wv.z + v.w * wv.w;
            }
        }
    }
    __syncthreads();
#pragma unroll
    for (int oo = 0; oo < 12; ++oo) smem[(obase + oo) * 128 + pxl] = lk(acc[oo]);
    __syncthreads();

    float acc2[12];
#pragma unroll
    for (int oo = 0; oo < 12; ++oo) acc2[oo] = sbr[obase + oo];
    for (int c = 0; c < CO; ++c) {
        const float in_c = smem[c * 128 + pxl];
#pragma unroll
        for (int oo = 0; oo < 12; ++oo) acc2[oo] += in_c * swt[c * CO + obase + oo];
    }
#pragma unroll
    for (int oo = 0; oo < 12; ++oo)
        out[((size_t)(b * CO + obase + oo) * HQ + h) * WL + j] = lk(acc2[oo]);
}

// ======= Kernel B: em_right (4x4 s4,1 pad 1,2) + leaky + rc 1x1 + leaky ======
// R4 structure (separate LDS, no union). 64 lanes * 4 px each x 4 o-quarters;
// grid 960. Edge cols via two aligned dwordx2 loads + cndmask (no scalar loads,
// no shuffles -- R6 showed shuffles+guarded loads regress).
__global__ __launch_bounds__(256) void k_right(
    const float* __restrict__ x, const float* __restrict__ w_em,
    const float* __restrict__ b_em, const float* __restrict__ w_rc,
    const float* __restrict__ b_rc, float* __restrict__ out)
{
    __shared__ float sw[CO * CIN * 16];
    __shared__ float em[CO * 256];
    __shared__ float swt[CO * CO];
    __shared__ float sbe[CO], sbr[CO];

    for (int i = threadIdx.x; i < CO * CIN * 16; i += 256) sw[i] = w_em[i];
    for (int i = threadIdx.x; i < CO * CO; i += 256) swt[i] = w_rc[(i % CO) * CO + (i / CO)];
    if (threadIdx.x < CO) { sbe[threadIdx.x] = b_em[threadIdx.x]; sbr[threadIdx.x] = b_rc[threadIdx.x]; }
    __syncthreads();

    const int t = threadIdx.x;
    const int L = t & 63, quarter = t >> 6;
    const int obase = quarter * 6;
    const int row = blockIdx.x / 5, jbase = (blockIdx.x % 5) * 256;
    const int b = row / HQ, h = row % HQ;

    // Edge handling (loop-invariant). Global col of local idx i is jbase+i.
    // Left pair @4L-2 (8B aligned): valid unless jbase==0 && L==0 (true pad);
    // clamp address there, mask value via vm1 (col 4L-1 valid iff jbase+4L>0).
    // Right pair @4L+4: cols jbase+4L+4/+5; both OOB only at jbase=1024,L=63
    // (even cols -> vp4 == vp5).
    const bool vm1 = (jbase + 4 * L) > 0;
    const bool vp  = (jbase + 4 * L + 4) < WIN;
    const int  om1 = vm1 ? (4 * L - 2) : 0;
    const int  op4 = vp  ? (4 * L + 4) : 0;

    float acc[4][6];
#pragma unroll
    for (int k = 0; k < 4; ++k)
#pragma unroll
        for (int oo = 0; oo < 6; ++oo) acc[k][oo] = sbe[obase + oo];

    for (int c = 0; c < CIN; ++c) {
#pragma unroll
        for (int kh = 0; kh < 4; ++kh) {
            const float* xr = x + ((size_t)(b * CIN + c) * HIN + 4 * h + kh) * WIN + jbase;
            const float4  v = *(const float4*)(xr + 4 * L);
            const float2  A = *(const float2*)(xr + om1);   // cols 4L-2, 4L-1
            const float2  C = *(const float2*)(xr + op4);   // cols 4L+4, 4L+5
            float in[7];
            in[0] = vm1 ? A.y : 0.f;
            in[1] = v.x; in[2] = v.y; in[3] = v.z; in[4] = v.w;
            in[5] = vp ? C.x : 0.f;
            in[6] = vp ? C.y : 0.f;
#pragma unroll
            for (int oo = 0; oo < 6; ++oo) {
                const float4 wv = *(const float4*)&sw[(((obase + oo) * CIN + c) * 4 + kh) * 4];
#pragma unroll
                for (int k = 0; k < 4; ++k)
                    acc[k][oo] += in[k] * wv.x + in[k + 1] * wv.y + in[k + 2] * wv.z + in[k + 3] * wv.w;
            }
        }
    }
#pragma unroll
    for (int oo = 0; oo < 6; ++oo) {
        float4 st = make_float4(lk(acc[0][oo]), lk(acc[1][oo]), lk(acc[2][oo]), lk(acc[3][oo]));
        *(float4*)&em[(obase + oo) * 256 + 4 * L] = st;
    }
    __syncthreads();

    float acc2[CO];
#pragma unroll
    for (int o = 0; o < CO; ++o) acc2[o] = sbr[o];
    for (int c = 0; c < CO; ++c) {
        const float in_c = em[c * 256 + t];
#pragma unroll
        for (int o = 0; o < CO; ++o) acc2[o] += in_c * swt[c * CO + o];
    }
#pragma unroll
    for (int o = 0; o < CO; ++o)
        out[((size_t)(b * CO + o) * HQ + h) * WR + jbase + t] = lk(acc2[o]);
}

// ====== Kernel C: cost volume + min/argmin + tf 1x1 + output assembly ========
// block 256 = 64 j-lanes x 4 waves (wave w owns d in [16w,16w+16)); grid 960.
// LDS layout: frs[c*324 + 2 + (col - colbase)], colbase = 4*j0-64; cols<0
// replicated with fr[c][0] (reference's lower clip; upper clip never fires).
// The +2 shift makes each (c, d-quad) gather group of 4 consecutive cols
// 16B-aligned -> one ds_read_b128 replaces 4 ds_read_b32 (96 vs 384 DS
// instrs/thread). Group addr = c*324 + 4*j - 4*D + 64 (D = d>>2); value i of
// the float4 pairs with d = 4D+3-i. Channel-ascending += of fabsf keeps costs
// bitwise-identical to prior passing rounds -> argmin tie behavior preserved.
__global__ __launch_bounds__(256) void k_cost(
    const float* __restrict__ fl, const float* __restrict__ fr,
    const float* __restrict__ wtf, const float* __restrict__ btf,
    float* __restrict__ out, float* __restrict__ cost)
{
    __shared__ float frs[CO * 324];       // 31104 B
    __shared__ float sbest[256];
    __shared__ int   sbd[256];

    const int t  = threadIdx.x;
    const int j  = t & 63;                 // lane = local col
    const int w  = t >> 6;                 // wave: d in [16w, 16w+16)
    const int jc = blockIdx.x % 5;
    const int r  = blockIdx.x / 5;
    const int h  = r % HQ, b = r / HQ;
    const int j0 = jc * 64;
    const int jg = j0 + j;
    const int colbase = 4 * j0 - 64;

    // stage 24 rows x 320 cols (coalesced; left-clip replication)
    for (int idx = t; idx < CO * 320; idx += 256) {
        const int c = idx / 320, Wd = idx % 320;
        const int col = colbase + Wd;
        frs[c * 324 + 2 + Wd] = fr[((size_t)(b * CO + c) * HQ + h) * WR + (col > 0 ? col : 0)];
    }
    __syncthreads();

    float acc[4][4];                       // [q][r], d = 16w + 4q + r
#pragma unroll
    for (int q = 0; q < 4; ++q)
#pragma unroll
        for (int rr = 0; rr < 4; ++rr) acc[q][rr] = 0.f;

    for (int c = 0; c < CO; ++c) {
        const float flc = fl[((size_t)(b * CO + c) * HQ + h) * WL + jg];
        const float* base = &frs[c * 324 + 4 * j + 64];
#pragma unroll
        for (int q = 0; q < 4; ++q) {
            const int D = 4 * w + q;
            const float4 v = *(const float4*)(base - 4 * D);  // 16B-aligned
            acc[q][0] += fabsf(flc - v.w);   // d = 4D
            acc[q][1] += fabsf(flc - v.z);   // d = 4D+1
            acc[q][2] += fabsf(flc - v.y);   // d = 4D+2
            acc[q][3] += fabsf(flc - v.x);   // d = 4D+3
        }
    }

    // cost volume writes (coalesced over jg)
#pragma unroll
    for (int q = 0; q < 4; ++q)
#pragma unroll
        for (int rr = 0; rr < 4; ++rr) {
            const int d = 16 * w + 4 * q + rr;
            cost[((size_t)(b * DMAX + d) * HQ + h) * WL + jg] = acc[q][rr];
        }

    // per-thread min / first-occurrence argmin (ascending d within wave range)
    float best = acc[0][0]; int bd = 16 * w;
#pragma unroll
    for (int q = 0; q < 4; ++q)
#pragma unroll
        for (int rr = 0; rr < 4; ++rr) {
            if (q == 0 && rr == 0) continue;
            const int d = 16 * w + 4 * q + rr;
            if (acc[q][rr] < best) { best = acc[q][rr]; bd = d; }
        }
    sbest[t] = best; sbd[t] = bd;
    __syncthreads();

    if (t < 64) {
        float cur = sbest[j]; int curd = sbd[j];
#pragma unroll
        for (int g = 1; g < 4; ++g) {
            const float v = sbest[g * 64 + j];
            if (v < cur) { cur = v; curd = sbd[g * 64 + j]; }
        }
        float flr[CO];
#pragma unroll
        for (int c = 0; c < CO; ++c) flr[c] = fl[((size_t)(b * CO + c) * HQ + h) * WL + jg];
#pragma unroll
        for (int o = 0; o < 13; ++o) {
            float a = btf[o] + wtf[o * 25] * cur;
#pragma unroll
            for (int c = 0; c < CO; ++c) a += wtf[o * 25 + 1 + c] * flr[c];
            out[((size_t)(b * 16 + 3 + o) * HQ + h) * WL + jg] = lk(a);
        }
        out[((size_t)(b * 16 + 0) * HQ + h) * WL + jg] = (float)curd;
        out[((size_t)(b * 16 + 1) * HQ + h) * WL + jg] = 0.f;
        out[((size_t)(b * 16 + 2) * HQ + h) * WL + jg] = 0.f;
    }
}

extern "C" void kernel_launch(void* const* d_in, const int* in_sizes, int n_in,
                              void* d_out, int out_size, void* d_ws, size_t ws_size,
                              hipStream_t stream) {
    const float* fl_in = (const float*)d_in[0];
    const float* fr_in = (const float*)d_in[1];
    // d_in[2] = max_disp (int) -- fixed 64
    const float* w_em = (const float*)d_in[3];
    const float* b_em = (const float*)d_in[4];
    const float* w_rc = (const float*)d_in[5];
    const float* b_rc = (const float*)d_in[6];
    const float* w_tf = (const float*)d_in[7];
    const float* b_tf = (const float*)d_in[8];

    float* out  = (float*)d_out;
    float* cost = out + (size_t)B_ * 16 * HQ * WL;

    float* fl_ws = (float*)d_ws;                               // [2,24,96,320]
    float* fr_ws = fl_ws + (size_t)B_ * CO * HQ * WL;          // [2,24,96,1280]

    hipLaunchKernelGGL(k_right, dim3(960), dim3(256), 0, stream,
                       fr_in, w_em, b_em, w_rc, b_rc, fr_ws);
    hipLaunchKernelGGL(k_left,  dim3(480), dim3(256), 0, stream,
                       fl_in, w_em, b_em, w_rc, b_rc, fl_ws);
    hipLaunchKernelGGL(k_cost,  dim3(960), dim3(256), 0, stream,
                       fl_ws, fr_ws, w_tf, b_tf, out, cost);
}